// Round 10
// baseline (196.034 us; speedup 1.0000x reference)
//
#include <hip/hip_runtime.h>
#include <hip/hip_bf16.h>

#define B_  4
#define S_  2048
#define D_  640
#define H_  10
#define KD_ 64
// M = B_*S_ = 8192; QKV fused N = 3*H_*KD_ = 1920; K = 640

typedef __attribute__((ext_vector_type(8))) short  short8;
typedef __attribute__((ext_vector_type(4))) short  short4v;
typedef __attribute__((ext_vector_type(4))) float  floatx4;
typedef __attribute__((ext_vector_type(2))) unsigned int uint2v;

// scalar cheap RNE bf16 (finite inputs only).
static __device__ __forceinline__ short f2bf_fast(float f) {
    unsigned int u = __float_as_uint(f);
    u += 0x7fffu + ((u >> 16) & 1u);
    return (short)(u >> 16);
}
// packed pair via HIP intrinsic (maps to v_cvt_pk_bf16_f32 where available).
static __device__ __forceinline__ unsigned int pack2bf(float a, float b) {
    union { __hip_bfloat162 h; unsigned int u; } c;
    c.h = __float22bfloat162_rn(float2{a, b});
    return c.u;
}

// async global->LDS DMA, 16 B/lane: lane i lands at ldsbase + i*16.
static __device__ __forceinline__ void gload_lds16(const void* gp, void* lp) {
    __builtin_amdgcn_global_load_lds(
        (const __attribute__((address_space(1))) unsigned int*)gp,
        (__attribute__((address_space(3))) unsigned int*)lp, 16, 0, 0);
}

// ---------------------------------------------------------------------------
// Kernel 1: fused prep — pack_x (blocks [0,5120)), transpose_w [5120,6320),
// transpose_wo [6320,6720). Branches are WG-uniform.
// ---------------------------------------------------------------------------
__global__ __launch_bounds__(256) void prep(
        const float* __restrict__ x,
        const float* __restrict__ Wq, const float* __restrict__ Wk,
        const float* __restrict__ Wv, const float* __restrict__ Wo,
        short* __restrict__ xb, short* __restrict__ BigT,
        short* __restrict__ WoT) {
    __shared__ float tile[32][33];
    int bid = blockIdx.x;
    if (bid < 5120) {
        int idx = (bid * 256 + threadIdx.x) * 4;
        float4 v = *(const float4*)(x + idx);
        uint2v o;
        o[0] = pack2bf(v.x, v.y);
        o[1] = pack2bf(v.z, v.w);
        *(uint2v*)(xb + idx) = o;
    } else if (bid < 6320) {
        int flat = bid - 5120;
        int bz = flat / 40, rem = flat % 40;
        int by = rem >> 1, bxx = rem & 1;
        int w = bz / 10, h = bz % 10;
        const float* W = ((w == 0) ? Wq : (w == 1) ? Wk : Wv) + h * 640 * 64;
        short* out = BigT + (w * 640 + h * 64) * 640;
        int c0 = bxx * 32;   // kd tile
        int r0 = by * 32;    // d tile
        int tx = threadIdx.x & 31, ty = threadIdx.x >> 5;
        #pragma unroll
        for (int k = 0; k < 4; ++k)
            tile[ty + 8 * k][tx] = W[(r0 + ty + 8 * k) * 64 + c0 + tx];
        __syncthreads();
        #pragma unroll
        for (int k = 0; k < 4; ++k)
            out[(c0 + ty + 8 * k) * 640 + r0 + tx] = f2bf_fast(tile[tx][ty + 8 * k]);
    } else {
        int flat = bid - 6320;                 // (20,20)
        int c0 = (flat % 20) * 32;             // n tile
        int r0 = (flat / 20) * 32;             // f tile
        int tx = threadIdx.x & 31, ty = threadIdx.x >> 5;
        #pragma unroll
        for (int k = 0; k < 4; ++k)
            tile[ty + 8 * k][tx] = Wo[(r0 + ty + 8 * k) * 640 + c0 + tx];
        __syncthreads();
        #pragma unroll
        for (int k = 0; k < 4; ++k)
            WoT[(c0 + ty + 8 * k) * 640 + r0 + tx] = f2bf_fast(tile[tx][ty + 8 * k]);
    }
}

// ===========================================================================
// GEMM v3: 128x128 tile, BK=32, double-buffered LDS (32 KB), one barrier per
// K-iter, DMA-after-barrier. ALL blocks operand-swapped: acc[nt][mt] holds
// Y^T (row = n-dim in quad*4+r, col = m-dim in lq) -> each lane's 4 values
// are CONTIGUOUS along n -> packed wide epilogue stores.
// ===========================================================================

// ---------------------------------------------------------------------------
// Kernel 2: fused QKV projection GEMM.  Y(8192x1920) = X(8192x640) @ BigT^T.
// Q/K: packed b64 stores (4 bf16 along kd). V: vtb[kd][s] stores (as R9).
// ---------------------------------------------------------------------------
__global__ __launch_bounds__(256) void qkv_gemm(
        const short* __restrict__ X, const short* __restrict__ BigT,
        short* __restrict__ qb, short* __restrict__ kb, short* __restrict__ vtb) {
    __shared__ __align__(16) short Ab[2][128][32];   // 16 KB
    __shared__ __align__(16) short Bb[2][128][32];   // 16 KB

    int wave = threadIdx.x >> 6;
    int lane = threadIdx.x & 63;
    int lq = lane & 15, quad = lane >> 4;
    int wm = (wave & 1) * 64, wn = (wave >> 1) * 64;
    int tm = blockIdx.x * 128;
    int tn = blockIdx.y * 128;

    int srow = lane >> 2;                               // 0..15
    int schunk = (lane & 3) ^ ((lane >> 3) & 3);        // XOR by (row>>1)&3
    const short* Asrc0 = X    + (tm + wave * 32 + srow) * 640 + schunk * 8;
    const short* Bsrc0 = BigT + (tn + wave * 32 + srow) * 640 + schunk * 8;
    const short* Asrc1 = Asrc0 + 16 * 640;
    const short* Bsrc1 = Bsrc0 + 16 * 640;

    floatx4 acc[4][4];   // [nt][mt], transposed orientation
    for (int a = 0; a < 4; ++a)
        for (int n = 0; n < 4; ++n)
            acc[a][n] = (floatx4){0.f, 0.f, 0.f, 0.f};

    int rsw = (lq >> 1) & 3;     // fragment-read XOR

    gload_lds16(Asrc0, &Ab[0][wave * 32][0]);
    gload_lds16(Asrc1, &Ab[0][wave * 32 + 16][0]);
    gload_lds16(Bsrc0, &Bb[0][wave * 32][0]);
    gload_lds16(Bsrc1, &Bb[0][wave * 32 + 16][0]);

    int p = 0;
    for (int k0 = 0; k0 < 640; k0 += 32) {
        __syncthreads();   // vmcnt(0) drain => buf[p] staged; buf[p^1] free
        if (k0 + 32 < 640) {
            int pn = p ^ 1;
            gload_lds16(Asrc0 + k0 + 32, &Ab[pn][wave * 32][0]);
            gload_lds16(Asrc1 + k0 + 32, &Ab[pn][wave * 32 + 16][0]);
            gload_lds16(Bsrc0 + k0 + 32, &Bb[pn][wave * 32][0]);
            gload_lds16(Bsrc1 + k0 + 32, &Bb[pn][wave * 32 + 16][0]);
        }

        short8 af[4], bf[4];
        #pragma unroll
        for (int t = 0; t < 4; ++t) {
            af[t] = *(const short8*)(&Ab[p][wm + t * 16 + lq][(quad ^ rsw) * 8]);
            bf[t] = *(const short8*)(&Bb[p][wn + t * 16 + lq][(quad ^ rsw) * 8]);
        }
        // swapped: acc[nt][mt] = Y^T block (row=n, col=m)
        #pragma unroll
        for (int nt = 0; nt < 4; ++nt)
            #pragma unroll
            for (int mt = 0; mt < 4; ++mt)
                acc[nt][mt] = __builtin_amdgcn_mfma_f32_16x16x32_bf16(
                    bf[nt], af[mt], acc[nt][mt], 0, 0, 0);
        p ^= 1;
    }

    if (tn < 1280) {
        // ---- Q/K: packed b64 stores, 4 consecutive kd per lane ----
        const float qscale = 0.18033688011112042f;  // (1/sqrt(64)) * log2(e)
        short* dst = (tn < 640) ? qb : kb;
        float scale = (tn < 640) ? qscale : 1.0f;
        #pragma unroll
        for (int nt = 0; nt < 4; ++nt) {
            int rem = (tn + wn + nt * 16) % 640;
            int hh = rem / 64;
            int kd0 = (rem % 64) + quad * 4;
            #pragma unroll
            for (int mt = 0; mt < 4; ++mt) {
                int m = tm + wm + mt * 16 + lq;
                int b = m >> 11, s = m & 2047;
                uint2v pk;
                pk[0] = pack2bf(acc[nt][mt][0] * scale, acc[nt][mt][1] * scale);
                pk[1] = pack2bf(acc[nt][mt][2] * scale, acc[nt][mt][3] * scale);
                *(uint2v*)(dst + ((b * H_ + hh) * S_ + s) * KD_ + kd0) = pk;
            }
        }
    } else {
        // ---- V: vtb[kd][s], 32B s-segments per inst (as R9) ----
        #pragma unroll
        for (int nt = 0; nt < 4; ++nt) {
            int rem = (tn + wn + nt * 16) - 1280;   // within V range [0,640)
            int hh = rem / 64;
            int kd0 = (rem % 64) + quad * 4;
            #pragma unroll
            for (int mt = 0; mt < 4; ++mt) {
                int m = tm + wm + mt * 16 + lq;
                int b = m >> 11, s = m & 2047;
                #pragma unroll
                for (int r = 0; r < 4; ++r) {
                    vtb[((b * H_ + hh) * KD_ + kd0 + r) * S_ + s] =
                        f2bf_fast(acc[nt][mt][r]);
                }
            }
        }
    }
}

// ---------------------------------------------------------------------------
// Kernel 3: flash attention v5 (frozen from R9).
// ---------------------------------------------------------------------------
__global__ __launch_bounds__(256, 3) void attn(
        const short* __restrict__ qb, const short* __restrict__ kbuf,
        const short* __restrict__ vtb, short* __restrict__ zb) {
    __shared__ __align__(16) short Kbuf[2][64][64];      // 16 KB
    __shared__ __align__(16) short Vbuf[2][64][64];      // 16 KB
    __shared__ __align__(16) short Pbuf[4][2][16][72];   // 18 KB, wave-private

    int wave = threadIdx.x >> 6;
    int lane = threadIdx.x & 63;
    int lq = lane & 15, quad = lane >> 4;

    int bx = blockIdx.x;               // 640 = 8 xcd * 5 bh * 16 qtiles
    int xcd = bx & 7, slot = bx >> 3;
    int bh = xcd * 5 + (slot >> 4);
    int qt = slot & 15;
    int b = bh / 10, h = bh % 10;
    int q0 = qt * 128;

    const short* qp = qb + (b * H_ + h) * S_ * KD_;
    const short* kp = kbuf + (b * H_ + h) * S_ * KD_;
    const short* vp = vtb + (b * H_ + h) * KD_ * S_;

    int r8 = lane >> 3;
    int g  = (lane & 7) ^ r8;          // XOR-swizzled 16B group
    const short* kg0 = kp + (wave * 16 + r8) * 64 + g * 8;
    const short* kg1 = kp + (wave * 16 + 8 + r8) * 64 + g * 8;
    const short* vg0 = vp + (wave * 16 + r8) * (long)S_ + g * 8;
    const short* vg1 = vp + (wave * 16 + 8 + r8) * (long)S_ + g * 8;

    short8 qA0, qA1, qB0, qB1;
    {
        int rowA = q0 + wave * 32 + lq;
        qA0 = *(const short8*)(qp + rowA * 64 + quad * 8);
        qA1 = *(const short8*)(qp + rowA * 64 + 32 + quad * 8);
        qB0 = *(const short8*)(qp + (rowA + 16) * 64 + quad * 8);
        qB1 = *(const short8*)(qp + (rowA + 16) * 64 + 32 + quad * 8);
    }

    short8 ones;
    #pragma unroll
    for (int i = 0; i < 8; ++i) ones[i] = (short)0x3F80;   // bf16 1.0

    floatx4 OA[4], OB[4];   // O^T accum: col=m=lq, row=kd_local
    for (int n = 0; n < 4; ++n) {
        OA[n] = (floatx4){0.f, 0.f, 0.f, 0.f};
        OB[n] = (floatx4){0.f, 0.f, 0.f, 0.f};
    }
    floatx4 lsvA = (floatx4){0.f, 0.f, 0.f, 0.f};   // row-sum accum (replicated)
    floatx4 lsvB = (floatx4){0.f, 0.f, 0.f, 0.f};

    gload_lds16(kg0, &Kbuf[0][wave * 16][0]);
    gload_lds16(kg1, &Kbuf[0][wave * 16 + 8][0]);
    gload_lds16(vg0, &Vbuf[0][wave * 16][0]);
    gload_lds16(vg1, &Vbuf[0][wave * 16 + 8][0]);

    int p = 0;
    int sw = lq & 7;

    for (int t0 = 0; t0 < S_; t0 += 64) {
        __syncthreads();   // vmcnt(0) drain => buf[p] staged; buf[p^1] free

        if (t0 + 64 < S_) {
            int pn = p ^ 1;
            gload_lds16(kg0 + (t0 + 64) * 64, &Kbuf[pn][wave * 16][0]);
            gload_lds16(kg1 + (t0 + 64) * 64, &Kbuf[pn][wave * 16 + 8][0]);
            gload_lds16(vg0 + (t0 + 64),      &Vbuf[pn][wave * 16][0]);
            gload_lds16(vg1 + (t0 + 64),      &Vbuf[pn][wave * 16 + 8][0]);
        }

        const short* Kb = &Kbuf[p][0][0];
        const short* Vb = &Vbuf[p][0][0];

        // ---- S^T = K·Q^T per 16-key block ----
        floatx4 sTA[4], sTB[4];
        #pragma unroll
        for (int kblk = 0; kblk < 4; ++kblk) {
            const short* krow = Kb + (kblk * 16 + lq) * 64;
            short8 bk0 = *(const short8*)(krow + (quad ^ sw) * 8);
            short8 bk1 = *(const short8*)(krow + ((quad + 4) ^ sw) * 8);
            floatx4 zA = (floatx4){0.f, 0.f, 0.f, 0.f};
            zA = __builtin_amdgcn_mfma_f32_16x16x32_bf16(bk0, qA0, zA, 0, 0, 0);
            sTA[kblk] = __builtin_amdgcn_mfma_f32_16x16x32_bf16(bk1, qA1, zA, 0, 0, 0);
            floatx4 zB = (floatx4){0.f, 0.f, 0.f, 0.f};
            zB = __builtin_amdgcn_mfma_f32_16x16x32_bf16(bk0, qB0, zB, 0, 0, 0);
            sTB[kblk] = __builtin_amdgcn_mfma_f32_16x16x32_bf16(bk1, qB1, zB, 0, 0, 0);
        }

        // ---- no-max softmax + packed P^T write ----
        #pragma unroll
        for (int kblk = 0; kblk < 4; ++kblk) {
            uint2v wa;
            wa[0] = pack2bf(__builtin_amdgcn_exp2f(sTA[kblk][0]),
                            __builtin_amdgcn_exp2f(sTA[kblk][1]));
            wa[1] = pack2bf(__builtin_amdgcn_exp2f(sTA[kblk][2]),
                            __builtin_amdgcn_exp2f(sTA[kblk][3]));
            *(uint2v*)(&Pbuf[wave][0][lq][kblk * 16 + quad * 4]) = wa;
            uint2v wb;
            wb[0] = pack2bf(__builtin_amdgcn_exp2f(sTB[kblk][0]),
                            __builtin_amdgcn_exp2f(sTB[kblk][1]));
            wb[1] = pack2bf(__builtin_amdgcn_exp2f(sTB[kblk][2]),
                            __builtin_amdgcn_exp2f(sTB[kblk][3]));
            *(uint2v*)(&Pbuf[wave][1][lq][kblk * 16 + quad * 4]) = wb;
        }

        // ---- O^T += V^T · P^T ; row-sums via ones-MFMA ----
        #pragma unroll
        for (int ts = 0; ts < 2; ++ts) {
            short8 pfA = *(const short8*)(&Pbuf[wave][0][lq][ts * 32 + quad * 8]);
            short8 pfB = *(const short8*)(&Pbuf[wave][1][lq][ts * 32 + quad * 8]);
            lsvA = __builtin_amdgcn_mfma_f32_16x16x32_bf16(ones, pfA, lsvA, 0, 0, 0);
            lsvB = __builtin_amdgcn_mfma_f32_16x16x32_bf16(ones, pfB, lsvB, 0, 0, 0);
            #pragma unroll
            for (int db = 0; db < 4; ++db) {
                const short* vrow = Vb + (db * 16 + lq) * 64;
                short8 bv = *(const short8*)(vrow + ((ts * 4 + quad) ^ sw) * 8);
                OA[db] = __builtin_amdgcn_mfma_f32_16x16x32_bf16(bv, pfA, OA[db], 0, 0, 0);
                OB[db] = __builtin_amdgcn_mfma_f32_16x16x32_bf16(bv, pfB, OB[db], 0, 0, 0);
            }
        }

        p ^= 1;
    }

    float invA = 1.0f / lsvA[0];
    float invB = 1.0f / lsvB[0];

    int sA = q0 + wave * 32 + lq;        // group A Q-row (lane-fixed)
    int sB = sA + 16;
    short* zrA = zb + (b * S_ + sA) * 640 + h * 64;
    short* zrB = zb + (b * S_ + sB) * 640 + h * 64;
    #pragma unroll
    for (int db = 0; db < 4; ++db) {
        uint2v za, zv;
        za[0] = pack2bf(OA[db][0] * invA, OA[db][1] * invA);
        za[1] = pack2bf(OA[db][2] * invA, OA[db][3] * invA);
        *(uint2v*)(zrA + db * 16 + quad * 4) = za;
        zv[0] = pack2bf(OB[db][0] * invB, OB[db][1] * invB);
        zv[1] = pack2bf(OB[db][2] * invB, OB[db][3] * invB);
        *(uint2v*)(zrB + db * 16 + quad * 4) = zv;
    }
}

// ---------------------------------------------------------------------------
// Kernel 4: output projection, GEMM v3 (swapped).  out = Z @ WoT^T, fp32.
// Epilogue: float4 stores (4 consecutive n per lane).
// ---------------------------------------------------------------------------
__global__ __launch_bounds__(256) void out_gemm(
        const short* __restrict__ Z, const short* __restrict__ WoT,
        float* __restrict__ out) {
    __shared__ __align__(16) short Ab[2][128][32];
    __shared__ __align__(16) short Bb[2][128][32];

    int wave = threadIdx.x >> 6;
    int lane = threadIdx.x & 63;
    int lq = lane & 15, quad = lane >> 4;
    int wm = (wave & 1) * 64, wn = (wave >> 1) * 64;
    int tm = blockIdx.x * 128;
    int tn = blockIdx.y * 128;

    int srow = lane >> 2;
    int schunk = (lane & 3) ^ ((lane >> 3) & 3);
    const short* Asrc0 = Z   + (tm + wave * 32 + srow) * 640 + schunk * 8;
    const short* Bsrc0 = WoT + (tn + wave * 32 + srow) * 640 + schunk * 8;
    const short* Asrc1 = Asrc0 + 16 * 640;
    const short* Bsrc1 = Bsrc0 + 16 * 640;

    floatx4 acc[4][4];   // [nt][mt], transposed orientation
    for (int a = 0; a < 4; ++a)
        for (int n = 0; n < 4; ++n)
            acc[a][n] = (floatx4){0.f, 0.f, 0.f, 0.f};

    int rsw = (lq >> 1) & 3;

    gload_lds16(Asrc0, &Ab[0][wave * 32][0]);
    gload_lds16(Asrc1, &Ab[0][wave * 32 + 16][0]);
    gload_lds16(Bsrc0, &Bb[0][wave * 32][0]);
    gload_lds16(Bsrc1, &Bb[0][wave * 32 + 16][0]);

    int p = 0;
    for (int k0 = 0; k0 < 640; k0 += 32) {
        __syncthreads();
        if (k0 + 32 < 640) {
            int pn = p ^ 1;
            gload_lds16(Asrc0 + k0 + 32, &Ab[pn][wave * 32][0]);
            gload_lds16(Asrc1 + k0 + 32, &Ab[pn][wave * 32 + 16][0]);
            gload_lds16(Bsrc0 + k0 + 32, &Bb[pn][wave * 32][0]);
            gload_lds16(Bsrc1 + k0 + 32, &Bb[pn][wave * 32 + 16][0]);
        }

        short8 af[4], bf[4];
        #pragma unroll
        for (int t = 0; t < 4; ++t) {
            af[t] = *(const short8*)(&Ab[p][wm + t * 16 + lq][(quad ^ rsw) * 8]);
            bf[t] = *(const short8*)(&Bb[p][wn + t * 16 + lq][(quad ^ rsw) * 8]);
        }
        #pragma unroll
        for (int nt = 0; nt < 4; ++nt)
            #pragma unroll
            for (int mt = 0; mt < 4; ++mt)
                acc[nt][mt] = __builtin_amdgcn_mfma_f32_16x16x32_bf16(
                    bf[nt], af[mt], acc[nt][mt], 0, 0, 0);
        p ^= 1;
    }

    #pragma unroll
    for (int nt = 0; nt < 4; ++nt) {
        int n0 = tn + wn + nt * 16 + quad * 4;
        #pragma unroll
        for (int mt = 0; mt < 4; ++mt) {
            int m = tm + wm + mt * 16 + lq;
            float4 v4 = make_float4(acc[nt][mt][0], acc[nt][mt][1],
                                    acc[nt][mt][2], acc[nt][mt][3]);
            *(float4*)(out + m * 640 + n0) = v4;
        }
    }
}

// ---------------------------------------------------------------------------
extern "C" void kernel_launch(void* const* d_in, const int* in_sizes, int n_in,
                              void* d_out, int out_size, void* d_ws, size_t ws_size,
                              hipStream_t stream) {
    const float* x  = (const float*)d_in[0];
    const float* Wq = (const float*)d_in[1];
    const float* Wk = (const float*)d_in[2];
    const float* Wv = (const float*)d_in[3];
    const float* Wo = (const float*)d_in[4];
    float* out = (float*)d_out;

    char* ws = (char*)d_ws;
    short* BigT = (short*)(ws);                    //  1920*640*2 = 2,457,600
    short* WoT  = (short*)(ws + 2457600);          //   640*640*2 =   819,200
    short* xb   = (short*)(ws + 3276800);          // 8192*640*2  = 10,485,760
    short* qb   = (short*)(ws + 13762560);
    short* kb   = (short*)(ws + 24248320);
    short* vtb  = (short*)(ws + 34734080);
    short* zb   = xb;   // xb dead after qkv_gemm; alias saves 10.5 MB of ws

    prep<<<dim3(6720), dim3(256), 0, stream>>>(x, Wq, Wk, Wv, Wo, xb, BigT, WoT);
    qkv_gemm<<<dim3(64, 15), dim3(256), 0, stream>>>(xb, BigT, qb, kb, vtb);
    attn<<<dim3(640), dim3(256), 0, stream>>>(qb, kb, vtb, zb);
    out_gemm<<<dim3(64, 5), dim3(256), 0, stream>>>(zb, WoT, out);
}

// Round 11
// 194.535 us; speedup vs baseline: 1.0077x; 1.0077x over previous
//
#include <hip/hip_runtime.h>
#include <hip/hip_bf16.h>

#define B_  4
#define S_  2048
#define D_  640
#define H_  10
#define KD_ 64
// M = B_*S_ = 8192; QKV fused N = 3*H_*KD_ = 1920; K = 640

typedef __attribute__((ext_vector_type(8))) short  short8;
typedef __attribute__((ext_vector_type(4))) short  short4v;
typedef __attribute__((ext_vector_type(4))) float  floatx4;
typedef __attribute__((ext_vector_type(2))) unsigned int uint2v;
typedef __attribute__((ext_vector_type(4))) unsigned int uint4v;

// scalar cheap RNE bf16 (finite inputs only).
static __device__ __forceinline__ short f2bf_fast(float f) {
    unsigned int u = __float_as_uint(f);
    u += 0x7fffu + ((u >> 16) & 1u);
    return (short)(u >> 16);
}
// packed pair via HIP intrinsic (maps to v_cvt_pk_bf16_f32 where available).
static __device__ __forceinline__ unsigned int pack2bf(float a, float b) {
    union { __hip_bfloat162 h; unsigned int u; } c;
    c.h = __float22bfloat162_rn(float2{a, b});
    return c.u;
}

// async global->LDS DMA, 16 B/lane: lane i lands at ldsbase + i*16.
static __device__ __forceinline__ void gload_lds16(const void* gp, void* lp) {
    __builtin_amdgcn_global_load_lds(
        (const __attribute__((address_space(1))) unsigned int*)gp,
        (__attribute__((address_space(3))) unsigned int*)lp, 16, 0, 0);
}

// ---------------------------------------------------------------------------
// Kernel 1: fused prep — pack_x (blocks [0,2560), 8 elems/thread),
// transpose_w [2560,3760) (Wq rows pre-scaled by qscale), transpose_wo
// [3760,4160). Branches are WG-uniform.
// ---------------------------------------------------------------------------
__global__ __launch_bounds__(256) void prep(
        const float* __restrict__ x,
        const float* __restrict__ Wq, const float* __restrict__ Wk,
        const float* __restrict__ Wv, const float* __restrict__ Wo,
        short* __restrict__ xb, short* __restrict__ BigT,
        short* __restrict__ WoT) {
    __shared__ float tile[32][33];
    int bid = blockIdx.x;
    if (bid < 2560) {
        int idx = (bid * 256 + threadIdx.x) * 8;
        float4 v0 = *(const float4*)(x + idx);
        float4 v1 = *(const float4*)(x + idx + 4);
        uint4v o;
        o[0] = pack2bf(v0.x, v0.y);
        o[1] = pack2bf(v0.z, v0.w);
        o[2] = pack2bf(v1.x, v1.y);
        o[3] = pack2bf(v1.z, v1.w);
        *(uint4v*)(xb + idx) = o;
    } else if (bid < 3760) {
        int flat = bid - 2560;
        int bz = flat / 40, rem = flat % 40;
        int by = rem >> 1, bxx = rem & 1;
        int w = bz / 10, h = bz % 10;
        const float* W = ((w == 0) ? Wq : (w == 1) ? Wk : Wv) + h * 640 * 64;
        // fold softmax scale * log2(e) into Q's weights
        const float qscale = 0.18033688011112042f;
        float scale = (w == 0) ? qscale : 1.0f;
        short* out = BigT + (w * 640 + h * 64) * 640;
        int c0 = bxx * 32;   // kd tile
        int r0 = by * 32;    // d tile
        int tx = threadIdx.x & 31, ty = threadIdx.x >> 5;
        #pragma unroll
        for (int k = 0; k < 4; ++k)
            tile[ty + 8 * k][tx] = W[(r0 + ty + 8 * k) * 64 + c0 + tx];
        __syncthreads();
        #pragma unroll
        for (int k = 0; k < 4; ++k)
            out[(c0 + ty + 8 * k) * 640 + r0 + tx] =
                f2bf_fast(tile[tx][ty + 8 * k] * scale);
    } else {
        int flat = bid - 3760;                 // (20,20)
        int c0 = (flat % 20) * 32;             // n tile
        int r0 = (flat / 20) * 32;             // f tile
        int tx = threadIdx.x & 31, ty = threadIdx.x >> 5;
        #pragma unroll
        for (int k = 0; k < 4; ++k)
            tile[ty + 8 * k][tx] = Wo[(r0 + ty + 8 * k) * 640 + c0 + tx];
        __syncthreads();
        #pragma unroll
        for (int k = 0; k < 4; ++k)
            WoT[(c0 + ty + 8 * k) * 640 + r0 + tx] = f2bf_fast(tile[tx][ty + 8 * k]);
    }
}

// ===========================================================================
// GEMM v3: 128x128 tile, BK=32, double-buffered LDS (32 KB), one barrier per
// K-iter, DMA-after-barrier. All blocks operand-swapped: acc[nt][mt] = Y^T.
// ===========================================================================

// ---------------------------------------------------------------------------
// Kernel 2: fused QKV projection GEMM.  Y(8192x1920) = X(8192x640) @ BigT^T.
// Q/K: packed b64 stores (4 bf16 along kd). V: vtb[kd][s] 32B-segment stores.
// qscale pre-folded into BigT -> no epilogue scaling.
// ---------------------------------------------------------------------------
__global__ __launch_bounds__(256) void qkv_gemm(
        const short* __restrict__ X, const short* __restrict__ BigT,
        short* __restrict__ qb, short* __restrict__ kb, short* __restrict__ vtb) {
    __shared__ __align__(16) short Ab[2][128][32];   // 16 KB
    __shared__ __align__(16) short Bb[2][128][32];   // 16 KB

    int wave = threadIdx.x >> 6;
    int lane = threadIdx.x & 63;
    int lq = lane & 15, quad = lane >> 4;
    int wm = (wave & 1) * 64, wn = (wave >> 1) * 64;
    int tm = blockIdx.x * 128;
    int tn = blockIdx.y * 128;

    int srow = lane >> 2;                               // 0..15
    int schunk = (lane & 3) ^ ((lane >> 3) & 3);        // XOR by (row>>1)&3
    const short* Asrc0 = X    + (tm + wave * 32 + srow) * 640 + schunk * 8;
    const short* Bsrc0 = BigT + (tn + wave * 32 + srow) * 640 + schunk * 8;
    const short* Asrc1 = Asrc0 + 16 * 640;
    const short* Bsrc1 = Bsrc0 + 16 * 640;

    floatx4 acc[4][4];   // [nt][mt], transposed orientation
    for (int a = 0; a < 4; ++a)
        for (int n = 0; n < 4; ++n)
            acc[a][n] = (floatx4){0.f, 0.f, 0.f, 0.f};

    int rsw = (lq >> 1) & 3;     // fragment-read XOR

    gload_lds16(Asrc0, &Ab[0][wave * 32][0]);
    gload_lds16(Asrc1, &Ab[0][wave * 32 + 16][0]);
    gload_lds16(Bsrc0, &Bb[0][wave * 32][0]);
    gload_lds16(Bsrc1, &Bb[0][wave * 32 + 16][0]);

    int p = 0;
    for (int k0 = 0; k0 < 640; k0 += 32) {
        __syncthreads();   // vmcnt(0) drain => buf[p] staged; buf[p^1] free
        if (k0 + 32 < 640) {
            int pn = p ^ 1;
            gload_lds16(Asrc0 + k0 + 32, &Ab[pn][wave * 32][0]);
            gload_lds16(Asrc1 + k0 + 32, &Ab[pn][wave * 32 + 16][0]);
            gload_lds16(Bsrc0 + k0 + 32, &Bb[pn][wave * 32][0]);
            gload_lds16(Bsrc1 + k0 + 32, &Bb[pn][wave * 32 + 16][0]);
        }

        short8 af[4], bf[4];
        #pragma unroll
        for (int t = 0; t < 4; ++t) {
            af[t] = *(const short8*)(&Ab[p][wm + t * 16 + lq][(quad ^ rsw) * 8]);
            bf[t] = *(const short8*)(&Bb[p][wn + t * 16 + lq][(quad ^ rsw) * 8]);
        }
        // swapped: acc[nt][mt] = Y^T block (row=n, col=m)
        #pragma unroll
        for (int nt = 0; nt < 4; ++nt)
            #pragma unroll
            for (int mt = 0; mt < 4; ++mt)
                acc[nt][mt] = __builtin_amdgcn_mfma_f32_16x16x32_bf16(
                    bf[nt], af[mt], acc[nt][mt], 0, 0, 0);
        p ^= 1;
    }

    if (tn < 1280) {
        // ---- Q/K: packed b64 stores, 4 consecutive kd per lane ----
        short* dst = (tn < 640) ? qb : kb;
        #pragma unroll
        for (int nt = 0; nt < 4; ++nt) {
            int rem = (tn + wn + nt * 16) % 640;
            int hh = rem / 64;
            int kd0 = (rem % 64) + quad * 4;
            #pragma unroll
            for (int mt = 0; mt < 4; ++mt) {
                int m = tm + wm + mt * 16 + lq;
                int b = m >> 11, s = m & 2047;
                uint2v pk;
                pk[0] = pack2bf(acc[nt][mt][0], acc[nt][mt][1]);
                pk[1] = pack2bf(acc[nt][mt][2], acc[nt][mt][3]);
                *(uint2v*)(dst + ((b * H_ + hh) * S_ + s) * KD_ + kd0) = pk;
            }
        }
    } else {
        // ---- V: vtb[kd][s], 32B s-segments per inst ----
        #pragma unroll
        for (int nt = 0; nt < 4; ++nt) {
            int rem = (tn + wn + nt * 16) - 1280;   // within V range [0,640)
            int hh = rem / 64;
            int kd0 = (rem % 64) + quad * 4;
            #pragma unroll
            for (int mt = 0; mt < 4; ++mt) {
                int m = tm + wm + mt * 16 + lq;
                int b = m >> 11, s = m & 2047;
                #pragma unroll
                for (int r = 0; r < 4; ++r) {
                    vtb[((b * H_ + hh) * KD_ + kd0 + r) * S_ + s] =
                        f2bf_fast(acc[nt][mt][r]);
                }
            }
        }
    }
}

// ---------------------------------------------------------------------------
// Kernel 3: flash attention v6 — S^T orientation, SCALAR per-lane row-sums
// (ones-MFMA dropped: it added 4 MFMA/iter + a serial dependency for work
// 8 VALU adds do off the critical path). Everything else frozen from R9/R10.
// ---------------------------------------------------------------------------
__global__ __launch_bounds__(256, 3) void attn(
        const short* __restrict__ qb, const short* __restrict__ kbuf,
        const short* __restrict__ vtb, short* __restrict__ zb) {
    __shared__ __align__(16) short Kbuf[2][64][64];      // 16 KB
    __shared__ __align__(16) short Vbuf[2][64][64];      // 16 KB
    __shared__ __align__(16) short Pbuf[4][2][16][72];   // 18 KB, wave-private

    int wave = threadIdx.x >> 6;
    int lane = threadIdx.x & 63;
    int lq = lane & 15, quad = lane >> 4;

    int bx = blockIdx.x;               // 640 = 8 xcd * 5 bh * 16 qtiles
    int xcd = bx & 7, slot = bx >> 3;
    int bh = xcd * 5 + (slot >> 4);
    int qt = slot & 15;
    int b = bh / 10, h = bh % 10;
    int q0 = qt * 128;

    const short* qp = qb + (b * H_ + h) * S_ * KD_;
    const short* kp = kbuf + (b * H_ + h) * S_ * KD_;
    const short* vp = vtb + (b * H_ + h) * KD_ * S_;

    int r8 = lane >> 3;
    int g  = (lane & 7) ^ r8;          // XOR-swizzled 16B group
    const short* kg0 = kp + (wave * 16 + r8) * 64 + g * 8;
    const short* kg1 = kp + (wave * 16 + 8 + r8) * 64 + g * 8;
    const short* vg0 = vp + (wave * 16 + r8) * (long)S_ + g * 8;
    const short* vg1 = vp + (wave * 16 + 8 + r8) * (long)S_ + g * 8;

    short8 qA0, qA1, qB0, qB1;
    {
        int rowA = q0 + wave * 32 + lq;
        qA0 = *(const short8*)(qp + rowA * 64 + quad * 8);
        qA1 = *(const short8*)(qp + rowA * 64 + 32 + quad * 8);
        qB0 = *(const short8*)(qp + (rowA + 16) * 64 + quad * 8);
        qB1 = *(const short8*)(qp + (rowA + 16) * 64 + 32 + quad * 8);
    }

    floatx4 OA[4], OB[4];   // O^T accum: col=m=lq, row=kd_local
    for (int n = 0; n < 4; ++n) {
        OA[n] = (floatx4){0.f, 0.f, 0.f, 0.f};
        OB[n] = (floatx4){0.f, 0.f, 0.f, 0.f};
    }
    float lsA = 0.f, lsB = 0.f;   // per-lane partial row-sum for m = lq

    gload_lds16(kg0, &Kbuf[0][wave * 16][0]);
    gload_lds16(kg1, &Kbuf[0][wave * 16 + 8][0]);
    gload_lds16(vg0, &Vbuf[0][wave * 16][0]);
    gload_lds16(vg1, &Vbuf[0][wave * 16 + 8][0]);

    int p = 0;
    int sw = lq & 7;

    for (int t0 = 0; t0 < S_; t0 += 64) {
        __syncthreads();   // vmcnt(0) drain => buf[p] staged; buf[p^1] free

        if (t0 + 64 < S_) {
            int pn = p ^ 1;
            gload_lds16(kg0 + (t0 + 64) * 64, &Kbuf[pn][wave * 16][0]);
            gload_lds16(kg1 + (t0 + 64) * 64, &Kbuf[pn][wave * 16 + 8][0]);
            gload_lds16(vg0 + (t0 + 64),      &Vbuf[pn][wave * 16][0]);
            gload_lds16(vg1 + (t0 + 64),      &Vbuf[pn][wave * 16 + 8][0]);
        }

        const short* Kb = &Kbuf[p][0][0];
        const short* Vb = &Vbuf[p][0][0];

        // ---- S^T = K·Q^T per 16-key block ----
        floatx4 sTA[4], sTB[4];
        #pragma unroll
        for (int kblk = 0; kblk < 4; ++kblk) {
            const short* krow = Kb + (kblk * 16 + lq) * 64;
            short8 bk0 = *(const short8*)(krow + (quad ^ sw) * 8);
            short8 bk1 = *(const short8*)(krow + ((quad + 4) ^ sw) * 8);
            floatx4 zA = (floatx4){0.f, 0.f, 0.f, 0.f};
            zA = __builtin_amdgcn_mfma_f32_16x16x32_bf16(bk0, qA0, zA, 0, 0, 0);
            sTA[kblk] = __builtin_amdgcn_mfma_f32_16x16x32_bf16(bk1, qA1, zA, 0, 0, 0);
            floatx4 zB = (floatx4){0.f, 0.f, 0.f, 0.f};
            zB = __builtin_amdgcn_mfma_f32_16x16x32_bf16(bk0, qB0, zB, 0, 0, 0);
            sTB[kblk] = __builtin_amdgcn_mfma_f32_16x16x32_bf16(bk1, qB1, zB, 0, 0, 0);
        }

        // ---- no-max softmax + packed P^T write + scalar row-sums ----
        #pragma unroll
        for (int kblk = 0; kblk < 4; ++kblk) {
            float a0 = __builtin_amdgcn_exp2f(sTA[kblk][0]);
            float a1 = __builtin_amdgcn_exp2f(sTA[kblk][1]);
            float a2 = __builtin_amdgcn_exp2f(sTA[kblk][2]);
            float a3 = __builtin_amdgcn_exp2f(sTA[kblk][3]);
            lsA += (a0 + a1) + (a2 + a3);
            uint2v wa; wa[0] = pack2bf(a0, a1); wa[1] = pack2bf(a2, a3);
            *(uint2v*)(&Pbuf[wave][0][lq][kblk * 16 + quad * 4]) = wa;
            float b0 = __builtin_amdgcn_exp2f(sTB[kblk][0]);
            float b1 = __builtin_amdgcn_exp2f(sTB[kblk][1]);
            float b2 = __builtin_amdgcn_exp2f(sTB[kblk][2]);
            float b3 = __builtin_amdgcn_exp2f(sTB[kblk][3]);
            lsB += (b0 + b1) + (b2 + b3);
            uint2v wb; wb[0] = pack2bf(b0, b1); wb[1] = pack2bf(b2, b3);
            *(uint2v*)(&Pbuf[wave][1][lq][kblk * 16 + quad * 4]) = wb;
        }

        // ---- O^T += V^T · P^T ----
        #pragma unroll
        for (int ts = 0; ts < 2; ++ts) {
            short8 pfA = *(const short8*)(&Pbuf[wave][0][lq][ts * 32 + quad * 8]);
            short8 pfB = *(const short8*)(&Pbuf[wave][1][lq][ts * 32 + quad * 8]);
            #pragma unroll
            for (int db = 0; db < 4; ++db) {
                const short* vrow = Vb + (db * 16 + lq) * 64;
                short8 bv = *(const short8*)(vrow + ((ts * 4 + quad) ^ sw) * 8);
                OA[db] = __builtin_amdgcn_mfma_f32_16x16x32_bf16(bv, pfA, OA[db], 0, 0, 0);
                OB[db] = __builtin_amdgcn_mfma_f32_16x16x32_bf16(bv, pfB, OB[db], 0, 0, 0);
            }
        }

        p ^= 1;
    }

    // ---- epilogue: 2-shuffle row-sum reduce (over quads), divide, store ----
    lsA += __shfl_xor(lsA, 16);
    lsA += __shfl_xor(lsA, 32);
    lsB += __shfl_xor(lsB, 16);
    lsB += __shfl_xor(lsB, 32);
    float invA = 1.0f / lsA, invB = 1.0f / lsB;

    int sA = q0 + wave * 32 + lq;        // group A Q-row (lane-fixed)
    int sB = sA + 16;
    short* zrA = zb + (b * S_ + sA) * 640 + h * 64;
    short* zrB = zb + (b * S_ + sB) * 640 + h * 64;
    #pragma unroll
    for (int db = 0; db < 4; ++db) {
        uint2v za, zv;
        za[0] = pack2bf(OA[db][0] * invA, OA[db][1] * invA);
        za[1] = pack2bf(OA[db][2] * invA, OA[db][3] * invA);
        *(uint2v*)(zrA + db * 16 + quad * 4) = za;
        zv[0] = pack2bf(OB[db][0] * invB, OB[db][1] * invB);
        zv[1] = pack2bf(OB[db][2] * invB, OB[db][3] * invB);
        *(uint2v*)(zrB + db * 16 + quad * 4) = zv;
    }
}

// ---------------------------------------------------------------------------
// Kernel 4: output projection, GEMM v3 (swapped).  out = Z @ WoT^T, fp32.
// Epilogue: float4 stores (4 consecutive n per lane).
// ---------------------------------------------------------------------------
__global__ __launch_bounds__(256) void out_gemm(
        const short* __restrict__ Z, const short* __restrict__ WoT,
        float* __restrict__ out) {
    __shared__ __align__(16) short Ab[2][128][32];
    __shared__ __align__(16) short Bb[2][128][32];

    int wave = threadIdx.x >> 6;
    int lane = threadIdx.x & 63;
    int lq = lane & 15, quad = lane >> 4;
    int wm = (wave & 1) * 64, wn = (wave >> 1) * 64;
    int tm = blockIdx.x * 128;
    int tn = blockIdx.y * 128;

    int srow = lane >> 2;
    int schunk = (lane & 3) ^ ((lane >> 3) & 3);
    const short* Asrc0 = Z   + (tm + wave * 32 + srow) * 640 + schunk * 8;
    const short* Bsrc0 = WoT + (tn + wave * 32 + srow) * 640 + schunk * 8;
    const short* Asrc1 = Asrc0 + 16 * 640;
    const short* Bsrc1 = Bsrc0 + 16 * 640;

    floatx4 acc[4][4];   // [nt][mt], transposed orientation
    for (int a = 0; a < 4; ++a)
        for (int n = 0; n < 4; ++n)
            acc[a][n] = (floatx4){0.f, 0.f, 0.f, 0.f};

    int rsw = (lq >> 1) & 3;

    gload_lds16(Asrc0, &Ab[0][wave * 32][0]);
    gload_lds16(Asrc1, &Ab[0][wave * 32 + 16][0]);
    gload_lds16(Bsrc0, &Bb[0][wave * 32][0]);
    gload_lds16(Bsrc1, &Bb[0][wave * 32 + 16][0]);

    int p = 0;
    for (int k0 = 0; k0 < 640; k0 += 32) {
        __syncthreads();
        if (k0 + 32 < 640) {
            int pn = p ^ 1;
            gload_lds16(Asrc0 + k0 + 32, &Ab[pn][wave * 32][0]);
            gload_lds16(Asrc1 + k0 + 32, &Ab[pn][wave * 32 + 16][0]);
            gload_lds16(Bsrc0 + k0 + 32, &Bb[pn][wave * 32][0]);
            gload_lds16(Bsrc1 + k0 + 32, &Bb[pn][wave * 32 + 16][0]);
        }

        short8 af[4], bf[4];
        #pragma unroll
        for (int t = 0; t < 4; ++t) {
            af[t] = *(const short8*)(&Ab[p][wm + t * 16 + lq][(quad ^ rsw) * 8]);
            bf[t] = *(const short8*)(&Bb[p][wn + t * 16 + lq][(quad ^ rsw) * 8]);
        }
        #pragma unroll
        for (int nt = 0; nt < 4; ++nt)
            #pragma unroll
            for (int mt = 0; mt < 4; ++mt)
                acc[nt][mt] = __builtin_amdgcn_mfma_f32_16x16x32_bf16(
                    bf[nt], af[mt], acc[nt][mt], 0, 0, 0);
        p ^= 1;
    }

    #pragma unroll
    for (int nt = 0; nt < 4; ++nt) {
        int n0 = tn + wn + nt * 16 + quad * 4;
        #pragma unroll
        for (int mt = 0; mt < 4; ++mt) {
            int m = tm + wm + mt * 16 + lq;
            float4 v4 = make_float4(acc[nt][mt][0], acc[nt][mt][1],
                                    acc[nt][mt][2], acc[nt][mt][3]);
            *(float4*)(out + m * 640 + n0) = v4;
        }
    }
}

// ---------------------------------------------------------------------------
extern "C" void kernel_launch(void* const* d_in, const int* in_sizes, int n_in,
                              void* d_out, int out_size, void* d_ws, size_t ws_size,
                              hipStream_t stream) {
    const float* x  = (const float*)d_in[0];
    const float* Wq = (const float*)d_in[1];
    const float* Wk = (const float*)d_in[2];
    const float* Wv = (const float*)d_in[3];
    const float* Wo = (const float*)d_in[4];
    float* out = (float*)d_out;

    char* ws = (char*)d_ws;
    short* BigT = (short*)(ws);                    //  1920*640*2 = 2,457,600
    short* WoT  = (short*)(ws + 2457600);          //   640*640*2 =   819,200
    short* xb   = (short*)(ws + 3276800);          // 8192*640*2  = 10,485,760
    short* qb   = (short*)(ws + 13762560);
    short* kb   = (short*)(ws + 24248320);
    short* vtb  = (short*)(ws + 34734080);
    short* zb   = (short*)(ws + 45219840);         // dedicated again (de-confound R10)

    prep<<<dim3(4160), dim3(256), 0, stream>>>(x, Wq, Wk, Wv, Wo, xb, BigT, WoT);
    qkv_gemm<<<dim3(64, 15), dim3(256), 0, stream>>>(xb, BigT, qb, kb, vtb);
    attn<<<dim3(640), dim3(256), 0, stream>>>(qb, kb, vtb, zb);
    out_gemm<<<dim3(64, 5), dim3(256), 0, stream>>>(zb, WoT, out);
}